// Round 6
// baseline (982.939 us; speedup 1.0000x reference)
//
#include <hip/hip_runtime.h>

typedef float v2f __attribute__((ext_vector_type(2)));

#define T_LEN 2048
#define NH    10
#define OUT_T 1439
#define TFIRST 608      // first output timestep (T - TAIL)
#define NSEQ  4096

static __device__ __forceinline__ v2f fma2(v2f a, v2f b, v2f c) {
  return __builtin_elementwise_fma(a, b, c);
}
static __device__ __forceinline__ v2f splat2(float v) { v2f r; r.x = v; r.y = v; return r; }
static __device__ __forceinline__ v2f mulsp(v2f a, float s) { v2f r; r.x = a.x*s; r.y = a.y*s; return r; }

// sigmoid(z) = rcp(1 + exp2(z * -log2(e)))
static __device__ __forceinline__ float fast_sigmoid(float z) {
  float e = __builtin_amdgcn_exp2f(z * -1.4426950408889634f);
  return __builtin_amdgcn_rcpf(1.0f + e);
}
// tanh(z) = 2*sigmoid(2z) - 1 ; overflow -> Inf -> rcp -> 0 -> -1 (saturates)
static __device__ __forceinline__ float fast_tanh(float z) {
  float e = __builtin_amdgcn_exp2f(z * -2.8853900817779268f);
  return __builtin_amdgcn_rcpf(1.0f + e) * 2.0f - 1.0f;
}

// Broadcast lane (16-group base + j) to all lanes of its 16-group (verified R2-R4):
// BitMode src = ((i & 0x10) | j) within each 32-half.
#define SWZB(v, j) __uint_as_float(__builtin_amdgcn_ds_swizzle( \
    (int)__float_as_uint(v), (((j) << 5) | 0x10)))

// DPP row_ror:N within rows of 16 (verified R1-R4): dest[i] = src[(i-N)&15]
#define ROR_F(v, N) __uint_as_float(__builtin_amdgcn_update_dpp( \
    0, (int)__float_as_uint(v), 0x120 + (N), 0xF, 0xF, true))

// 4 sequences per wave; 16 lanes per sequence; lane u<10 owns hidden unit u
// (all four gates, packed (i,f)/(g,o) in v2f). Lanes u=10..15 carry fc1 rows
// folded into the layer-1 "g" slot (which receives tanh) — FC head is free.
//
// R5 SCHEDULE (latency-shadow reorder of the verified R4 pipeline):
//   1. issue load x(n+2)            [consumed NEXT iter -> full-iter shadow]
//   2. L0 gates+acts (t=n+1)        [needs only old r]
//   3. issue r' = bcast h0(n+1)     [hides under the whole L1 phase]
//   4. L1 gates (t=n): r-part, then q-part
//   5. L1 acts -> h1(n); issue q' = bcast h1(n)
//   6. fc2 (off-chain) fills q' shadow; q' additionally shadowed by next
//      iteration's L0 phase + L1 r-part.
__global__ void __launch_bounds__(64, 1)
lstm_fused(const float* __restrict__ x,
           const float* __restrict__ w_ih0, const float* __restrict__ w_hh0,
           const float* __restrict__ b_ih0, const float* __restrict__ b_hh0,
           const float* __restrict__ w_ih1, const float* __restrict__ w_hh1,
           const float* __restrict__ b_ih1, const float* __restrict__ b_hh1,
           const float* __restrict__ fc1_w, const float* __restrict__ fc1_b,
           const float* __restrict__ fc2_w, const float* __restrict__ fc2_b,
           float* __restrict__ out)
{
  const int lane = threadIdx.x;       // 0..63
  const int grp  = lane >> 4;         // sequence within wave (0..3) == 16-group
  const int u    = lane & 15;         // unit slot within group
  const int seq  = (int)blockIdx.x * 4 + grp;

  v2f whh0_if[NH], whh0_go[NH], wih1_if[NH], wih1_go[NH], whh1_if[NH], whh1_go[NH];
  v2f b0_if, b0_go, b1_if, b1_go, wx_if, wx_go;
  b0_if = b0_go = b1_if = b1_go = wx_if = wx_go = splat2(0.f);
#pragma unroll
  for (int j = 0; j < NH; ++j) {
    whh0_if[j] = splat2(0.f); whh0_go[j] = splat2(0.f);
    wih1_if[j] = splat2(0.f); wih1_go[j] = splat2(0.f);
    whh1_if[j] = splat2(0.f); whh1_go[j] = splat2(0.f);
  }

  if (u < NH) {
    const int ri = 0*NH+u, rf = 1*NH+u, rg = 2*NH+u, ro = 3*NH+u;
    wx_if.x = w_ih0[ri]; wx_if.y = w_ih0[rf];
    wx_go.x = w_ih0[rg]; wx_go.y = w_ih0[ro];
    b0_if.x = b_ih0[ri] + b_hh0[ri]; b0_if.y = b_ih0[rf] + b_hh0[rf];
    b0_go.x = b_ih0[rg] + b_hh0[rg]; b0_go.y = b_ih0[ro] + b_hh0[ro];
    b1_if.x = b_ih1[ri] + b_hh1[ri]; b1_if.y = b_ih1[rf] + b_hh1[rf];
    b1_go.x = b_ih1[rg] + b_hh1[rg]; b1_go.y = b_ih1[ro] + b_hh1[ro];
#pragma unroll
    for (int j = 0; j < NH; ++j) {
      whh0_if[j].x = w_hh0[ri*NH+j]; whh0_if[j].y = w_hh0[rf*NH+j];
      whh0_go[j].x = w_hh0[rg*NH+j]; whh0_go[j].y = w_hh0[ro*NH+j];
      wih1_if[j].x = w_ih1[ri*NH+j]; wih1_if[j].y = w_ih1[rf*NH+j];
      wih1_go[j].x = w_ih1[rg*NH+j]; wih1_go[j].y = w_ih1[ro*NH+j];
      whh1_if[j].x = w_hh1[ri*NH+j]; whh1_if[j].y = w_hh1[rf*NH+j];
      whh1_go[j].x = w_hh1[rg*NH+j]; whh1_go[j].y = w_hh1[ro*NH+j];
    }
  } else {
    b1_go.x = fc1_b[u - NH];          // fc1 bias in the L1 "g" slot (gets tanh)
#pragma unroll
    for (int j = 0; j < NH; ++j) whh1_go[j].x = fc1_w[(u - NH)*NH + j];
  }

  const float fc2wl = (u >= NH) ? fc2_w[u - NH] : 0.f;
  const float fc2bl = fc2_b[0];

  const float* xp   = x + (size_t)seq * T_LEN;
  float*       outp = out + (size_t)seq * OUT_T;

  // ---- prologue: layer 0 at t=0 (h0(-1)=0, c0(-1)=0) ----
  float c0, c1 = 0.f;
  float r0,r1,r2,r3,r4,r5,r6,r7,r8,r9;       // bcast of h0(n)   (current)
  float q0,q1,q2,q3,q4,q5,q6,q7,q8,q9;       // bcast of h1(n-1)
  {
    const float x0 = xp[0];
    const v2f g0if = fma2(wx_if, splat2(x0), b0_if);
    const v2f g0go = fma2(wx_go, splat2(x0), b0_go);
    const float si = fast_sigmoid(g0if.x);
    const float tg = fast_tanh(g0go.x);
    const float so = fast_sigmoid(g0go.y);
    c0 = si * tg;
    const float h0 = so * fast_tanh(c0);
    r0 = SWZB(h0,0); r1 = SWZB(h0,1); r2 = SWZB(h0,2); r3 = SWZB(h0,3);
    r4 = SWZB(h0,4); r5 = SWZB(h0,5); r6 = SWZB(h0,6); r7 = SWZB(h0,7);
    r8 = SWZB(h0,8); r9 = SWZB(h0,9);
    q0=q1=q2=q3=q4=q5=q6=q7=q8=q9 = 0.f;
  }
  float xv = xp[1];                          // x(n+1) for the first iteration

#pragma unroll 1
  for (int n = 0; n < T_LEN; ++n) {
    // ---- 1. prefetch x(n+2): consumed next iteration ----
    const int tn2 = (n + 2 < T_LEN) ? (n + 2) : (T_LEN - 1);
    const float xn2 = xp[tn2];

    // ---- 2. L0 gates (t=n+1), needs only old r; dual accumulators ----
    v2f aA = fma2(wx_if, splat2(xv), b0_if);
    v2f gA = fma2(wx_go, splat2(xv), b0_go);
    v2f aB = mulsp(whh0_if[1], r1);
    v2f gB = mulsp(whh0_go[1], r1);
#define L0T(j, hv, AC, GC) { const v2f s = splat2(hv); \
    AC = fma2(whh0_if[j], s, AC); GC = fma2(whh0_go[j], s, GC); }
    L0T(0,r0,aA,gA) L0T(2,r2,aA,gA) L0T(3,r3,aB,gB) L0T(4,r4,aA,gA)
    L0T(5,r5,aB,gB) L0T(6,r6,aA,gA) L0T(7,r7,aB,gB) L0T(8,r8,aA,gA)
    L0T(9,r9,aB,gB)
#undef L0T

    // ---- L0 activations -> h0(n+1) ----
    const v2f g0if = aA + aB;
    const v2f g0go = gA + gB;
    const float si0 = fast_sigmoid(g0if.x);
    const float sf0 = fast_sigmoid(g0if.y);
    const float tg0 = fast_tanh(g0go.x);
    const float so0 = fast_sigmoid(g0go.y);
    c0 = sf0 * c0 + si0 * tg0;
    const float h0n = so0 * fast_tanh(c0);

    // ---- 3. issue r' = bcast h0(n+1); hides under the whole L1 phase ----
    const float s0 = SWZB(h0n,0), s1 = SWZB(h0n,1), s2 = SWZB(h0n,2),
                s3 = SWZB(h0n,3), s4 = SWZB(h0n,4), s5 = SWZB(h0n,5),
                s6 = SWZB(h0n,6), s7 = SWZB(h0n,7), s8 = SWZB(h0n,8),
                s9 = SWZB(h0n,9);

    // ---- 4. L1 gates (t=n): r-part first (old r), then q-part ----
    v2f cA = fma2(wih1_if[0], splat2(r0), b1_if);
    v2f hA = fma2(wih1_go[0], splat2(r0), b1_go);
    v2f cB = mulsp(wih1_if[1], r1);
    v2f hB = mulsp(wih1_go[1], r1);
#define L1I(j, hv, AC, GC) { const v2f s = splat2(hv); \
    AC = fma2(wih1_if[j], s, AC); GC = fma2(wih1_go[j], s, GC); }
    L1I(2,r2,cA,hA) L1I(3,r3,cB,hB) L1I(4,r4,cA,hA) L1I(5,r5,cB,hB)
    L1I(6,r6,cA,hA) L1I(7,r7,cB,hB) L1I(8,r8,cA,hA) L1I(9,r9,cB,hB)
#undef L1I
    v2f cC = mulsp(whh1_if[0], q0);
    v2f hC = mulsp(whh1_go[0], q0);
    v2f cD = mulsp(whh1_if[1], q1);
    v2f hD = mulsp(whh1_go[1], q1);
#define L1R(j, hv, AC, GC) { const v2f s = splat2(hv); \
    AC = fma2(whh1_if[j], s, AC); GC = fma2(whh1_go[j], s, GC); }
    L1R(2,q2,cC,hC) L1R(3,q3,cD,hD) L1R(4,q4,cC,hC) L1R(5,q5,cD,hD)
    L1R(6,q6,cC,hC) L1R(7,q7,cD,hD) L1R(8,q8,cC,hC) L1R(9,q9,cD,hD)
#undef L1R

    // ---- 5. L1 activations -> h1(n); issue q' ----
    const v2f g1if = (cA + cB) + (cC + cD);
    const v2f g1go = (hA + hB) + (hC + hD);
    const float si1 = fast_sigmoid(g1if.x);
    const float sf1 = fast_sigmoid(g1if.y);
    const float tg1 = fast_tanh(g1go.x);           // fc lanes: tanh(fc1(h1(n-1)))
    const float so1 = fast_sigmoid(g1go.y);
    c1 = sf1 * c1 + si1 * tg1;
    const float h1n = so1 * fast_tanh(c1);

    q0 = SWZB(h1n,0); q1 = SWZB(h1n,1); q2 = SWZB(h1n,2); q3 = SWZB(h1n,3);
    q4 = SWZB(h1n,4); q5 = SWZB(h1n,5); q6 = SWZB(h1n,6); q7 = SWZB(h1n,7);
    q8 = SWZB(h1n,8); q9 = SWZB(h1n,9);

    // ---- 6. fc2 (off-chain; fills the q' latency shadow) ----
    if (n > TFIRST) {                              // n in [609,2047] -> out idx 0..1438
      float y = tg1 * fc2wl;                       // zero on lanes u<10
      y += ROR_F(y, 8);
      y += ROR_F(y, 4);
      y += ROR_F(y, 2);
      y += ROR_F(y, 1);                            // all 16 lanes hold row sum
      if (u == 0) outp[n - 1 - TFIRST] = y + fc2bl;
    }

    // ---- register rename for next iteration ----
    r0=s0; r1=s1; r2=s2; r3=s3; r4=s4; r5=s5; r6=s6; r7=s7; r8=s8; r9=s9;
    xv = xn2;
  }
}

extern "C" void kernel_launch(void* const* d_in, const int* in_sizes, int n_in,
                              void* d_out, int out_size, void* d_ws, size_t ws_size,
                              hipStream_t stream) {
  const float* x     = (const float*)d_in[0];
  const float* w_ih0 = (const float*)d_in[1];
  const float* w_hh0 = (const float*)d_in[2];
  const float* b_ih0 = (const float*)d_in[3];
  const float* b_hh0 = (const float*)d_in[4];
  const float* w_ih1 = (const float*)d_in[5];
  const float* w_hh1 = (const float*)d_in[6];
  const float* b_ih1 = (const float*)d_in[7];
  const float* b_hh1 = (const float*)d_in[8];
  const float* fc1_w = (const float*)d_in[9];
  const float* fc1_b = (const float*)d_in[10];
  const float* fc2_w = (const float*)d_in[11];
  const float* fc2_b = (const float*)d_in[12];
  float* out = (float*)d_out;

  lstm_fused<<<dim3(NSEQ / 4), dim3(64), 0, stream>>>(
      x, w_ih0, w_hh0, b_ih0, b_hh0, w_ih1, w_hh1, b_ih1, b_hh1,
      fc1_w, fc1_b, fc2_w, fc2_b, out);
}

// Round 7
// 760.153 us; speedup vs baseline: 1.2931x; 1.2931x over previous
//
#include <hip/hip_runtime.h>

typedef float v2f __attribute__((ext_vector_type(2)));

#define T_LEN 2048
#define NH    10
#define OUT_T 1439
#define TFIRST 608      // first output timestep (T - TAIL)
#define NSEQ  4096
#define CH    8         // steps per hand-off chunk
#define NCH   (T_LEN / CH)

static __device__ __forceinline__ v2f fma2(v2f a, v2f b, v2f c) {
  return __builtin_elementwise_fma(a, b, c);
}
static __device__ __forceinline__ v2f splat2(float v) { v2f r; r.x = v; r.y = v; return r; }
static __device__ __forceinline__ v2f mulsp(v2f a, float s) { v2f r; r.x = a.x*s; r.y = a.y*s; return r; }

// sigmoid(z) = rcp(1 + exp2(z * -log2(e)))
static __device__ __forceinline__ float fast_sigmoid(float z) {
  float e = __builtin_amdgcn_exp2f(z * -1.4426950408889634f);
  return __builtin_amdgcn_rcpf(1.0f + e);
}
// tanh(z) = 2*sigmoid(2z) - 1 ; overflow -> Inf -> rcp -> 0 -> -1 (saturates)
static __device__ __forceinline__ float fast_tanh(float z) {
  float e = __builtin_amdgcn_exp2f(z * -2.8853900817779268f);
  return __builtin_amdgcn_rcpf(1.0f + e) * 2.0f - 1.0f;
}

// Broadcast lane (16-group base + j) to all lanes of its 16-group (verified R2-R5):
// BitMode src = ((i & 0x10) | j) within each 32-half.
#define SWZB(v, j) __uint_as_float(__builtin_amdgcn_ds_swizzle( \
    (int)__float_as_uint(v), (((j) << 5) | 0x10)))

// DPP row_ror:N within rows of 16 (verified R1-R5): dest[i] = src[(i-N)&15]
#define ROR_F(v, N) __uint_as_float(__builtin_amdgcn_update_dpp( \
    0, (int)__float_as_uint(v), 0x120 + (N), 0xF, 0xF, true))

// WAVE-SPECIALIZED PRODUCER/CONSUMER (R6):
//   Workgroup = 2 waves, 4 sequences. Wave A (wid=0): layer-0 recurrence for
//   the 4 seqs, publishes h0(t) chunks (CH=8 steps) into double-buffered LDS.
//   Wave B (wid=1): layer-1 recurrence + folded fc1/fc2, one chunk behind,
//   reading h0 via broadcast LDS loads. L1 never feeds back to L0, so the
//   pipeline is one-way; one __syncthreads per chunk (256 total).
//   2 waves/SIMD, each ~half the per-step issue of the R4 monolith: one
//   wave's dependency stalls are filled by the other wave's issue.
// Per-seq lane layout within a wave (unchanged from R4): 16 lanes/seq,
// lane u<10 owns hidden unit u, gates packed (i,f)/(g,o) in v2f; B's lanes
// u=10..15 carry fc1 rows folded into the L1 "g" slot (which receives tanh).
__global__ void __launch_bounds__(128, 2)
lstm_fused(const float* __restrict__ x,
           const float* __restrict__ w_ih0, const float* __restrict__ w_hh0,
           const float* __restrict__ b_ih0, const float* __restrict__ b_hh0,
           const float* __restrict__ w_ih1, const float* __restrict__ w_hh1,
           const float* __restrict__ b_ih1, const float* __restrict__ b_hh1,
           const float* __restrict__ fc1_w, const float* __restrict__ fc1_b,
           const float* __restrict__ fc2_w, const float* __restrict__ fc2_b,
           float* __restrict__ out)
{
  __shared__ float h0buf[2][CH][64];

  const int tid  = threadIdx.x;       // 0..127
  const int wid  = tid >> 6;          // 0 = A (layer0), 1 = B (layer1+fc)
  const int lane = tid & 63;
  const int grp  = lane >> 4;         // sequence within wave (0..3)
  const int u    = lane & 15;         // unit slot within group
  const int seq  = (int)blockIdx.x * 4 + grp;

  // Unified register meaning per wave:
  //   A: wA = w_hh0, wx = w_ih0, bb = b_ih0+b_hh0            (wB unused = 0)
  //   B: wA = w_ih1 (h0 input), wB = w_hh1 (+fc1), bb = b_ih1+b_hh1
  v2f wA_if[NH], wA_go[NH], wB_if[NH], wB_go[NH];
  v2f wx_if, wx_go, bb_if, bb_go;
  wx_if = wx_go = bb_if = bb_go = splat2(0.f);
#pragma unroll
  for (int j = 0; j < NH; ++j) {
    wA_if[j] = splat2(0.f); wA_go[j] = splat2(0.f);
    wB_if[j] = splat2(0.f); wB_go[j] = splat2(0.f);
  }

  if (u < NH) {
    const int ri = 0*NH+u, rf = 1*NH+u, rg = 2*NH+u, ro = 3*NH+u;
    if (wid == 0) {
      wx_if.x = w_ih0[ri]; wx_if.y = w_ih0[rf];
      wx_go.x = w_ih0[rg]; wx_go.y = w_ih0[ro];
      bb_if.x = b_ih0[ri] + b_hh0[ri]; bb_if.y = b_ih0[rf] + b_hh0[rf];
      bb_go.x = b_ih0[rg] + b_hh0[rg]; bb_go.y = b_ih0[ro] + b_hh0[ro];
#pragma unroll
      for (int j = 0; j < NH; ++j) {
        wA_if[j].x = w_hh0[ri*NH+j]; wA_if[j].y = w_hh0[rf*NH+j];
        wA_go[j].x = w_hh0[rg*NH+j]; wA_go[j].y = w_hh0[ro*NH+j];
      }
    } else {
      bb_if.x = b_ih1[ri] + b_hh1[ri]; bb_if.y = b_ih1[rf] + b_hh1[rf];
      bb_go.x = b_ih1[rg] + b_hh1[rg]; bb_go.y = b_ih1[ro] + b_hh1[ro];
#pragma unroll
      for (int j = 0; j < NH; ++j) {
        wA_if[j].x = w_ih1[ri*NH+j]; wA_if[j].y = w_ih1[rf*NH+j];
        wA_go[j].x = w_ih1[rg*NH+j]; wA_go[j].y = w_ih1[ro*NH+j];
        wB_if[j].x = w_hh1[ri*NH+j]; wB_if[j].y = w_hh1[rf*NH+j];
        wB_go[j].x = w_hh1[rg*NH+j]; wB_go[j].y = w_hh1[ro*NH+j];
      }
    }
  } else if (wid == 1) {
    bb_go.x = fc1_b[u - NH];            // fc1 bias in the L1 "g" slot (gets tanh)
#pragma unroll
    for (int j = 0; j < NH; ++j) wB_go[j].x = fc1_w[(u - NH)*NH + j];
  }

  const float fc2wl = (wid == 1 && u >= NH) ? fc2_w[u - NH] : 0.f;
  const float fc2bl = fc2_b[0];

  const float* xp   = x + (size_t)seq * T_LEN;
  float*       outp = out + (size_t)seq * OUT_T;

  float c = 0.f;                       // A: c0 ; B: c1
  float r0=0.f,r1=0.f,r2=0.f,r3=0.f,r4=0.f,r5=0.f,r6=0.f,r7=0.f,r8=0.f,r9=0.f;
  float xv = (wid == 0) ? xp[0] : 0.f;

  // ---- A: produce steps t0..t0+7 into h0buf[m&1] ----
  auto a_chunk = [&](int m) {
    const int t0 = m * CH;
#pragma unroll 1
    for (int s = 0; s < CH; ++s) {
      const int t  = t0 + s;
      const int tn = (t + 1 < T_LEN) ? (t + 1) : (T_LEN - 1);
      const float xn = xp[tn];
      v2f aA = fma2(wx_if, splat2(xv), bb_if);
      v2f gA = fma2(wx_go, splat2(xv), bb_go);
      v2f aB = mulsp(wA_if[1], r1);
      v2f gB = mulsp(wA_go[1], r1);
#define L0T(j, hv, AC, GC) { const v2f sp = splat2(hv); \
      AC = fma2(wA_if[j], sp, AC); GC = fma2(wA_go[j], sp, GC); }
      L0T(0,r0,aA,gA) L0T(2,r2,aA,gA) L0T(3,r3,aB,gB) L0T(4,r4,aA,gA)
      L0T(5,r5,aB,gB) L0T(6,r6,aA,gA) L0T(7,r7,aB,gB) L0T(8,r8,aA,gA)
      L0T(9,r9,aB,gB)
#undef L0T
      const v2f gif = aA + aB;
      const v2f ggo = gA + gB;
      const float si = fast_sigmoid(gif.x);
      const float sf = fast_sigmoid(gif.y);
      const float tg = fast_tanh(ggo.x);
      const float so = fast_sigmoid(ggo.y);
      c = sf * c + si * tg;
      const float h0n = so * fast_tanh(c);   // pad lanes: finite garbage, never read
      h0buf[m & 1][s][lane] = h0n;
      r0 = SWZB(h0n,0); r1 = SWZB(h0n,1); r2 = SWZB(h0n,2); r3 = SWZB(h0n,3);
      r4 = SWZB(h0n,4); r5 = SWZB(h0n,5); r6 = SWZB(h0n,6); r7 = SWZB(h0n,7);
      r8 = SWZB(h0n,8); r9 = SWZB(h0n,9);
      xv = xn;
    }
  };

  // ---- B: consume steps t0..t0+7 from h0buf[m&1]; r regs hold bcast h1(t-1) ----
  auto b_chunk = [&](int m) {
    const int t0 = m * CH;
#pragma unroll 1
    for (int s = 0; s < CH; ++s) {
      const int t = t0 + s;
      const float* hb = &h0buf[m & 1][s][grp * 16];
      const float p0 = hb[0], p1 = hb[1], p2 = hb[2], p3 = hb[3], p4 = hb[4],
                  p5 = hb[5], p6 = hb[6], p7 = hb[7], p8 = hb[8], p9 = hb[9];
      // q-part (h1 recurrent + fc1), consumes r = bcast h1(t-1)
      v2f cC = fma2(wB_if[0], splat2(r0), bb_if);
      v2f hC = fma2(wB_go[0], splat2(r0), bb_go);
      v2f cD = mulsp(wB_if[1], r1);
      v2f hD = mulsp(wB_go[1], r1);
#define L1R(j, hv, AC, GC) { const v2f sp = splat2(hv); \
      AC = fma2(wB_if[j], sp, AC); GC = fma2(wB_go[j], sp, GC); }
      L1R(2,r2,cC,hC) L1R(3,r3,cD,hD) L1R(4,r4,cC,hC) L1R(5,r5,cD,hD)
      L1R(6,r6,cC,hC) L1R(7,r7,cD,hD) L1R(8,r8,cC,hC) L1R(9,r9,cD,hD)
#undef L1R
      // r-part (h0 input), consumes the LDS broadcast reads
      v2f cA = mulsp(wA_if[0], p0);
      v2f hA = mulsp(wA_go[0], p0);
      v2f cB = mulsp(wA_if[1], p1);
      v2f hB = mulsp(wA_go[1], p1);
#define L1I(j, hv, AC, GC) { const v2f sp = splat2(hv); \
      AC = fma2(wA_if[j], sp, AC); GC = fma2(wA_go[j], sp, GC); }
      L1I(2,p2,cA,hA) L1I(3,p3,cB,hB) L1I(4,p4,cA,hA) L1I(5,p5,cB,hB)
      L1I(6,p6,cA,hA) L1I(7,p7,cB,hB) L1I(8,p8,cA,hA) L1I(9,p9,cB,hB)
#undef L1I
      const v2f gif = (cA + cB) + (cC + cD);
      const v2f ggo = (hA + hB) + (hC + hD);
      const float si1 = fast_sigmoid(gif.x);
      const float sf1 = fast_sigmoid(gif.y);
      const float tg1 = fast_tanh(ggo.x);        // fc lanes: tanh(fc1(h1(t-1)))
      const float so1 = fast_sigmoid(ggo.y);
      c = sf1 * c + si1 * tg1;
      const float h1n = so1 * fast_tanh(c);
      r0 = SWZB(h1n,0); r1 = SWZB(h1n,1); r2 = SWZB(h1n,2); r3 = SWZB(h1n,3);
      r4 = SWZB(h1n,4); r5 = SWZB(h1n,5); r6 = SWZB(h1n,6); r7 = SWZB(h1n,7);
      r8 = SWZB(h1n,8); r9 = SWZB(h1n,9);
      // fc2: output fc(h1(t-1)) for t in [609,2047] -> idx 0..1438
      if (t > TFIRST) {
        float y = tg1 * fc2wl;                   // zero on lanes u<10
        y += ROR_F(y, 8);
        y += ROR_F(y, 4);
        y += ROR_F(y, 2);
        y += ROR_F(y, 1);                        // whole 16-group holds the sum
        if (u == 0) outp[t - 1 - TFIRST] = y + fc2bl;
      }
    }
  };

  // ---- pipeline: A one chunk ahead of B ----
  if (wid == 0) a_chunk(0);
#pragma unroll 1
  for (int i = 0; i < NCH; ++i) {
    __syncthreads();
    if (wid == 0) {
      if (i + 1 < NCH) a_chunk(i + 1);
    } else {
      b_chunk(i);
    }
  }
}

extern "C" void kernel_launch(void* const* d_in, const int* in_sizes, int n_in,
                              void* d_out, int out_size, void* d_ws, size_t ws_size,
                              hipStream_t stream) {
  const float* x     = (const float*)d_in[0];
  const float* w_ih0 = (const float*)d_in[1];
  const float* w_hh0 = (const float*)d_in[2];
  const float* b_ih0 = (const float*)d_in[3];
  const float* b_hh0 = (const float*)d_in[4];
  const float* w_ih1 = (const float*)d_in[5];
  const float* w_hh1 = (const float*)d_in[6];
  const float* b_ih1 = (const float*)d_in[7];
  const float* b_hh1 = (const float*)d_in[8];
  const float* fc1_w = (const float*)d_in[9];
  const float* fc1_b = (const float*)d_in[10];
  const float* fc2_w = (const float*)d_in[11];
  const float* fc2_b = (const float*)d_in[12];
  float* out = (float*)d_out;

  lstm_fused<<<dim3(NSEQ / 4), dim3(128), 0, stream>>>(
      x, w_ih0, w_hh0, b_ih0, b_hh0, w_ih1, w_hh1, b_ih1, b_hh1,
      fc1_w, fc1_b, fc2_w, fc2_b, out);
}

// Round 8
// 735.721 us; speedup vs baseline: 1.3360x; 1.0332x over previous
//
#include <hip/hip_runtime.h>

typedef float v2f __attribute__((ext_vector_type(2)));

#define T_LEN 2048
#define NH    10
#define OUT_T 1439
#define TFIRST 608      // first output timestep: out[k] = fc(h1(TFIRST+k))
#define NSEQ  4096
#define CH    8         // steps per hand-off chunk
#define NCH   (T_LEN / CH)      // 256
#define MFIRST (TFIRST / CH)    // 76: first chunk containing outputs

static __device__ __forceinline__ v2f fma2(v2f a, v2f b, v2f c) {
  return __builtin_elementwise_fma(a, b, c);
}
static __device__ __forceinline__ v2f splat2(float v) { v2f r; r.x = v; r.y = v; return r; }
static __device__ __forceinline__ v2f mulsp(v2f a, float s) { v2f r; r.x = a.x*s; r.y = a.y*s; return r; }

// sigmoid(z) = rcp(1 + exp2(z * -log2(e)))
static __device__ __forceinline__ float fast_sigmoid(float z) {
  float e = __builtin_amdgcn_exp2f(z * -1.4426950408889634f);
  return __builtin_amdgcn_rcpf(1.0f + e);
}
// tanh(z) = 2*sigmoid(2z) - 1 ; overflow -> Inf -> rcp -> 0 -> -1 (saturates)
static __device__ __forceinline__ float fast_tanh(float z) {
  float e = __builtin_amdgcn_exp2f(z * -2.8853900817779268f);
  return __builtin_amdgcn_rcpf(1.0f + e) * 2.0f - 1.0f;
}

// DPP row_ror:N within rows of 16 (verified R1-R6): dest[i] = src[(i-N)&15]
#define ROR_F(v, N) __uint_as_float(__builtin_amdgcn_update_dpp( \
    0, (int)__float_as_uint(v), 0x120 + (N), 0xF, 0xF, true))

// 3-WAVE SPECIALIZED PIPELINE (R7, extends verified R6 skeleton):
//   Workgroup = 3 waves x 64, 4 sequences (16 lanes/seq, lane u<10 owns unit
//   u, gates packed (i,f)/(g,o) in v2f).
//   Wave A: layer-0 recurrence -> h0buf ; Wave B: layer-1 -> h1buf (1 chunk
//   behind) ; Wave C: fc head from h1buf (2 chunks behind).
//   h-broadcast = LDS write + b128/b64 vector readback (in-order same-wave
//   DS, verified R0) instead of 10 ds_swizzles: 2.4x fewer DS ops.
//   Chunk bodies fully unrolled (imm-offset addressing, no per-step loop).
//   Round r: A does chunk r, B chunk r-1, C chunk r-2; double-buffered LDS
//   gives parity separation for every concurrent producer/consumer pair;
//   single textual __syncthreads per round.
__global__ void __launch_bounds__(192, 3)
lstm_fused(const float* __restrict__ x,
           const float* __restrict__ w_ih0, const float* __restrict__ w_hh0,
           const float* __restrict__ b_ih0, const float* __restrict__ b_hh0,
           const float* __restrict__ w_ih1, const float* __restrict__ w_hh1,
           const float* __restrict__ b_ih1, const float* __restrict__ b_hh1,
           const float* __restrict__ fc1_w, const float* __restrict__ fc1_b,
           const float* __restrict__ fc2_w, const float* __restrict__ fc2_b,
           float* __restrict__ out)
{
  __shared__ __align__(16) float h0buf[2][CH][64];
  __shared__ __align__(16) float h1buf[2][CH][64];

  const int tid  = threadIdx.x;       // 0..191
  const int wid  = tid / 64;          // 0=A(L0) 1=B(L1) 2=C(FC)
  const int lane = tid & 63;
  const int grp  = lane >> 4;         // sequence within wave (0..3)
  const int u    = lane & 15;         // unit slot within group
  const int seq  = (int)blockIdx.x * 4 + grp;

  // Unified register file across the three roles:
  //   A: wIF/wGO = w_hh0 rows, wx = w_ih0 col, bb = b_ih0+b_hh0
  //   B: wIF/wGO = w_ih1 rows, vIF/vGO = w_hh1 rows, bb = b_ih1+b_hh1
  //   C: fcw[j] = fc1 row, fcb = fc1 bias, fc2wl = fc2 weight
  v2f wIF[NH], wGO[NH], vIF[NH], vGO[NH];
  v2f wx_if, wx_go, bb_if, bb_go;
  wx_if = wx_go = bb_if = bb_go = splat2(0.f);
#pragma unroll
  for (int j = 0; j < NH; ++j) {
    wIF[j] = splat2(0.f); wGO[j] = splat2(0.f);
    vIF[j] = splat2(0.f); vGO[j] = splat2(0.f);
  }
  float fcw[NH];
#pragma unroll
  for (int j = 0; j < NH; ++j) fcw[j] = 0.f;
  float fcb = 0.f, fc2wl = 0.f;
  const float fc2bl = fc2_b[0];

  if (wid == 0) {
    if (u < NH) {
      const int ri = 0*NH+u, rf = 1*NH+u, rg = 2*NH+u, ro = 3*NH+u;
      wx_if.x = w_ih0[ri]; wx_if.y = w_ih0[rf];
      wx_go.x = w_ih0[rg]; wx_go.y = w_ih0[ro];
      bb_if.x = b_ih0[ri] + b_hh0[ri]; bb_if.y = b_ih0[rf] + b_hh0[rf];
      bb_go.x = b_ih0[rg] + b_hh0[rg]; bb_go.y = b_ih0[ro] + b_hh0[ro];
#pragma unroll
      for (int j = 0; j < NH; ++j) {
        wIF[j].x = w_hh0[ri*NH+j]; wIF[j].y = w_hh0[rf*NH+j];
        wGO[j].x = w_hh0[rg*NH+j]; wGO[j].y = w_hh0[ro*NH+j];
      }
    }
  } else if (wid == 1) {
    if (u < NH) {
      const int ri = 0*NH+u, rf = 1*NH+u, rg = 2*NH+u, ro = 3*NH+u;
      bb_if.x = b_ih1[ri] + b_hh1[ri]; bb_if.y = b_ih1[rf] + b_hh1[rf];
      bb_go.x = b_ih1[rg] + b_hh1[rg]; bb_go.y = b_ih1[ro] + b_hh1[ro];
#pragma unroll
      for (int j = 0; j < NH; ++j) {
        wIF[j].x = w_ih1[ri*NH+j]; wIF[j].y = w_ih1[rf*NH+j];
        wGO[j].x = w_ih1[rg*NH+j]; wGO[j].y = w_ih1[ro*NH+j];
        vIF[j].x = w_hh1[ri*NH+j]; vIF[j].y = w_hh1[rf*NH+j];
        vGO[j].x = w_hh1[rg*NH+j]; vGO[j].y = w_hh1[ro*NH+j];
      }
    }
  } else {
    if (u < 6) {
      fcb = fc1_b[u]; fc2wl = fc2_w[u];
#pragma unroll
      for (int j = 0; j < NH; ++j) fcw[j] = fc1_w[u*NH + j];
    }
  }

  const float* xp   = x + (size_t)seq * T_LEN;
  float*       outp = out + (size_t)seq * OUT_T;

  float c = 0.f;                                  // A: c0 ; B: c1
  float r0=0.f,r1=0.f,r2=0.f,r3=0.f,r4=0.f,r5=0.f,r6=0.f,r7=0.f,r8=0.f,r9=0.f;

  // ---- A: produce h0 for steps m*CH .. m*CH+7 into h0buf[m&1] ----
  auto a_chunk = [&](int m) {
    float* hb = &h0buf[m & 1][0][0];
    const float* hr = &h0buf[m & 1][0][grp * 16];
    const float* xq = xp + m * CH;
#pragma unroll
    for (int s = 0; s < CH; ++s) {
      const float xv = xq[s];
      v2f aA = fma2(wx_if, splat2(xv), bb_if);
      v2f gA = fma2(wx_go, splat2(xv), bb_go);
      v2f aB = mulsp(wIF[1], r1);
      v2f gB = mulsp(wGO[1], r1);
#define L0T(j, hv, AC, GC) { const v2f sp = splat2(hv); \
      AC = fma2(wIF[j], sp, AC); GC = fma2(wGO[j], sp, GC); }
      L0T(0,r0,aA,gA) L0T(2,r2,aA,gA) L0T(3,r3,aB,gB) L0T(4,r4,aA,gA)
      L0T(5,r5,aB,gB) L0T(6,r6,aA,gA) L0T(7,r7,aB,gB) L0T(8,r8,aA,gA)
      L0T(9,r9,aB,gB)
#undef L0T
      const v2f gif = aA + aB;
      const v2f ggo = gA + gB;
      const float si = fast_sigmoid(gif.x);
      const float sf = fast_sigmoid(gif.y);
      const float tg = fast_tanh(ggo.x);
      const float so = fast_sigmoid(ggo.y);
      c = sf * c + si * tg;
      const float h0n = so * fast_tanh(c);        // pad lanes: bounded, never read
      hb[s*64 + lane] = h0n;
      // vector readback = broadcast for next step (in-order same-wave DS)
      const float4 va = *(const float4*)(hr + s*64);
      const float4 vb = *(const float4*)(hr + s*64 + 4);
      const float2 vc = *(const float2*)(hr + s*64 + 8);
      r0=va.x; r1=va.y; r2=va.z; r3=va.w;
      r4=vb.x; r5=vb.y; r6=vb.z; r7=vb.w;
      r8=vc.x; r9=vc.y;
    }
  };

  // ---- B: consume h0 chunk m, produce h1 chunk m into h1buf[m&1] ----
  auto b_chunk = [&](int m) {
    const float* hbi = &h0buf[m & 1][0][grp * 16];
    float* ob = &h1buf[m & 1][0][0];
    const float* orr = &h1buf[m & 1][0][grp * 16];
#pragma unroll
    for (int s = 0; s < CH; ++s) {
      const float4 pa = *(const float4*)(hbi + s*64);
      const float4 pb = *(const float4*)(hbi + s*64 + 4);
      const float2 pc = *(const float2*)(hbi + s*64 + 8);
      // h0-input part
      v2f cA = fma2(wIF[0], splat2(pa.x), bb_if);
      v2f hA = fma2(wGO[0], splat2(pa.x), bb_go);
      v2f cB = mulsp(wIF[1], pa.y);
      v2f hB = mulsp(wGO[1], pa.y);
#define L1I(j, hv, AC, GC) { const v2f sp = splat2(hv); \
      AC = fma2(wIF[j], sp, AC); GC = fma2(wGO[j], sp, GC); }
      L1I(2,pa.z,cA,hA) L1I(3,pa.w,cB,hB) L1I(4,pb.x,cA,hA) L1I(5,pb.y,cB,hB)
      L1I(6,pb.z,cA,hA) L1I(7,pb.w,cB,hB) L1I(8,pc.x,cA,hA) L1I(9,pc.y,cB,hB)
#undef L1I
      // h1-recurrent part (r holds readback of h1(t-1))
      v2f cC = mulsp(vIF[0], r0);
      v2f hC = mulsp(vGO[0], r0);
      v2f cD = mulsp(vIF[1], r1);
      v2f hD = mulsp(vGO[1], r1);
#define L1R(j, hv, AC, GC) { const v2f sp = splat2(hv); \
      AC = fma2(vIF[j], sp, AC); GC = fma2(vGO[j], sp, GC); }
      L1R(2,r2,cC,hC) L1R(3,r3,cD,hD) L1R(4,r4,cC,hC) L1R(5,r5,cD,hD)
      L1R(6,r6,cC,hC) L1R(7,r7,cD,hD) L1R(8,r8,cC,hC) L1R(9,r9,cD,hD)
#undef L1R
      const v2f gif = (cA + cB) + (cC + cD);
      const v2f ggo = (hA + hB) + (hC + hD);
      const float si1 = fast_sigmoid(gif.x);
      const float sf1 = fast_sigmoid(gif.y);
      const float tg1 = fast_tanh(ggo.x);
      const float so1 = fast_sigmoid(ggo.y);
      c = sf1 * c + si1 * tg1;
      const float h1n = so1 * fast_tanh(c);       // pad lanes: bounded, never read
      ob[s*64 + lane] = h1n;
      const float4 va = *(const float4*)(orr + s*64);
      const float4 vb = *(const float4*)(orr + s*64 + 4);
      const float2 vc = *(const float2*)(orr + s*64 + 8);
      r0=va.x; r1=va.y; r2=va.z; r3=va.w;
      r4=vb.x; r5=vb.y; r6=vb.z; r7=vb.w;
      r8=vc.x; r9=vc.y;
    }
  };

  // ---- C: fc head on h1 chunk m: out[t-TFIRST] = fc2(tanh(fc1(h1(t)))) ----
  auto c_chunk = [&](int m) {
    const float* hb = &h1buf[m & 1][0][grp * 16];
    const int t0 = m * CH;
    float* oq = outp + (t0 - TFIRST);
#pragma unroll
    for (int s = 0; s < CH; ++s) {
      if (t0 + s < TFIRST + OUT_T) {              // t <= 2046 (uniform)
        const float4 pa = *(const float4*)(hb + s*64);
        const float4 pb = *(const float4*)(hb + s*64 + 4);
        const float2 pc = *(const float2*)(hb + s*64 + 8);
        float acc = __builtin_fmaf(pa.x, fcw[0], fcb);
        acc = __builtin_fmaf(pa.y, fcw[1], acc);
        acc = __builtin_fmaf(pa.z, fcw[2], acc);
        acc = __builtin_fmaf(pa.w, fcw[3], acc);
        acc = __builtin_fmaf(pb.x, fcw[4], acc);
        acc = __builtin_fmaf(pb.y, fcw[5], acc);
        acc = __builtin_fmaf(pb.z, fcw[6], acc);
        acc = __builtin_fmaf(pb.w, fcw[7], acc);
        acc = __builtin_fmaf(pc.x, fcw[8], acc);
        acc = __builtin_fmaf(pc.y, fcw[9], acc);
        float y = fast_tanh(acc) * fc2wl;         // nonzero only on lanes u<6
        y += ROR_F(y, 8);
        y += ROR_F(y, 4);
        y += ROR_F(y, 2);
        y += ROR_F(y, 1);                         // whole 16-group holds the sum
        if (u == 0) oq[s] = y + fc2bl;
      }
    }
  };

  // ---- pipeline: A -> B -> C, one chunk apart each ----
#pragma unroll 1
  for (int r = 0; r < NCH + 2; ++r) {
    if (wid == 0) {
      if (r < NCH) a_chunk(r);
    } else if (wid == 1) {
      if (r >= 1 && r < NCH + 1) b_chunk(r - 1);
    } else {
      const int m = r - 2;
      if (m >= MFIRST && m < NCH) c_chunk(m);
    }
    __syncthreads();
  }
}

extern "C" void kernel_launch(void* const* d_in, const int* in_sizes, int n_in,
                              void* d_out, int out_size, void* d_ws, size_t ws_size,
                              hipStream_t stream) {
  const float* x     = (const float*)d_in[0];
  const float* w_ih0 = (const float*)d_in[1];
  const float* w_hh0 = (const float*)d_in[2];
  const float* b_ih0 = (const float*)d_in[3];
  const float* b_hh0 = (const float*)d_in[4];
  const float* w_ih1 = (const float*)d_in[5];
  const float* w_hh1 = (const float*)d_in[6];
  const float* b_ih1 = (const float*)d_in[7];
  const float* b_hh1 = (const float*)d_in[8];
  const float* fc1_w = (const float*)d_in[9];
  const float* fc1_b = (const float*)d_in[10];
  const float* fc2_w = (const float*)d_in[11];
  const float* fc2_b = (const float*)d_in[12];
  float* out = (float*)d_out;

  lstm_fused<<<dim3(NSEQ / 4), dim3(192), 0, stream>>>(
      x, w_ih0, w_hh0, b_ih0, b_hh0, w_ih1, w_hh1, b_ih1, b_hh1,
      fc1_w, fc1_b, fc2_w, fc2_b, out);
}

// Round 9
// 724.025 us; speedup vs baseline: 1.3576x; 1.0162x over previous
//
#include <hip/hip_runtime.h>

typedef float v2f __attribute__((ext_vector_type(2)));

#define T_LEN 2048
#define NH    10
#define OUT_T 1439
#define TFIRST 608      // first output timestep: out[k] = fc(h1(TFIRST+k))
#define NSEQ  4096
#define CH    16        // steps per hand-off chunk
#define NCH   (T_LEN / CH)      // 128
#define MFIRST (TFIRST / CH)    // 38 (exact)

#define KSIG (-1.4426950408889634f)   // -log2(e)      (sigmoid arg scale)
#define KTAN (-2.8853900817779268f)   // -2*log2(e)    (tanh arg scale)

static __device__ __forceinline__ v2f fma2(v2f a, v2f b, v2f c) {
  return __builtin_elementwise_fma(a, b, c);
}
static __device__ __forceinline__ v2f splat2(float v) { v2f r; r.x = v; r.y = v; return r; }
static __device__ __forceinline__ v2f mulsp(v2f a, float s) { v2f r; r.x = a.x*s; r.y = a.y*s; return r; }
static __device__ __forceinline__ float rcp1p(float e) {   // rcp(1+e)
  return __builtin_amdgcn_rcpf(1.0f + e);
}

// DPP row_ror:N within rows of 16 (verified R1-R7): dest[i] = src[(i-N)&15]
#define ROR_F(v, N) __uint_as_float(__builtin_amdgcn_update_dpp( \
    0, (int)__float_as_uint(v), 0x120 + (N), 0xF, 0xF, true))

// 2-WAVE BALANCED PIPELINE (R8, from verified R7 3-wave version):
//   Wave A: layer-0 recurrence -> h0buf, PLUS the fc head (reads h1buf two
//           chunks back) — fc fills A's slack since the wall is B-bound.
//   Wave B: layer-1 recurrence -> h1buf, one chunk behind A. No fc fold.
//   Weight pre-scaling: sigmoid rows scaled by KSIG, tanh rows by KTAN at
//   load time; cell state kept as c' = KTAN*c. Activations become
//   rcp(1+exp2(g)) directly — saves ~10 VALU instrs per wave-step.
//   Round r: A does L0 chunk r + fc chunk r-2; B does L1 chunk r-1.
//   Double-buffered LDS gives parity separation for all pairs:
//     A writes h0[r&1]; B reads h0[(r-1)&1], writes h1[(r-1)&1];
//     A reads h1[(r-2)&1] = h1[r&1]. One __syncthreads per round (130 total).
// Lane layout per wave (verified R0-R7): 4 seqs, 16 lanes/seq, lane u<10
// owns unit u, gates packed (i,f)/(g,o) in v2f; broadcast = LDS write +
// b128/b64 readback (in-order same-wave DS).
__global__ void __launch_bounds__(128, 2)
lstm_fused(const float* __restrict__ x,
           const float* __restrict__ w_ih0, const float* __restrict__ w_hh0,
           const float* __restrict__ b_ih0, const float* __restrict__ b_hh0,
           const float* __restrict__ w_ih1, const float* __restrict__ w_hh1,
           const float* __restrict__ b_ih1, const float* __restrict__ b_hh1,
           const float* __restrict__ fc1_w, const float* __restrict__ fc1_b,
           const float* __restrict__ fc2_w, const float* __restrict__ fc2_b,
           float* __restrict__ out)
{
  __shared__ __align__(16) float h0buf[2][CH][64];
  __shared__ __align__(16) float h1buf[2][CH][64];

  const int tid  = threadIdx.x;       // 0..127
  const int wid  = tid >> 6;          // 0=A(L0+FC) 1=B(L1)
  const int lane = tid & 63;
  const int grp  = lane >> 4;         // sequence within wave (0..3)
  const int u    = lane & 15;         // unit slot within group
  const int seq  = (int)blockIdx.x * 4 + grp;

  //   A: wIF/wGO = KSIG/KTAN-scaled w_hh0 rows, wx = scaled w_ih0, bb = scaled biases
  //   B: wIF/wGO = scaled w_ih1 rows, vIF/vGO = scaled w_hh1 rows, bb = scaled biases
  v2f wIF[NH], wGO[NH], vIF[NH], vGO[NH];
  v2f wx_if, wx_go, bb_if, bb_go;
  wx_if = wx_go = bb_if = bb_go = splat2(0.f);
#pragma unroll
  for (int j = 0; j < NH; ++j) {
    wIF[j] = splat2(0.f); wGO[j] = splat2(0.f);
    vIF[j] = splat2(0.f); vGO[j] = splat2(0.f);
  }
  float fcw[NH];
#pragma unroll
  for (int j = 0; j < NH; ++j) fcw[j] = 0.f;
  float fcb = 0.f, fc2w2 = 0.f, fc2wn = 0.f;
  const float fc2bl = fc2_b[0];

  if (wid == 0) {
    if (u < NH) {
      const int ri = 0*NH+u, rf = 1*NH+u, rg = 2*NH+u, ro = 3*NH+u;
      wx_if.x = KSIG * w_ih0[ri];            wx_if.y = KSIG * w_ih0[rf];
      wx_go.x = KTAN * w_ih0[rg];            wx_go.y = KSIG * w_ih0[ro];
      bb_if.x = KSIG * (b_ih0[ri] + b_hh0[ri]); bb_if.y = KSIG * (b_ih0[rf] + b_hh0[rf]);
      bb_go.x = KTAN * (b_ih0[rg] + b_hh0[rg]); bb_go.y = KSIG * (b_ih0[ro] + b_hh0[ro]);
#pragma unroll
      for (int j = 0; j < NH; ++j) {
        wIF[j].x = KSIG * w_hh0[ri*NH+j]; wIF[j].y = KSIG * w_hh0[rf*NH+j];
        wGO[j].x = KTAN * w_hh0[rg*NH+j]; wGO[j].y = KSIG * w_hh0[ro*NH+j];
      }
    }
    if (u < 6) {                 // fc head: fc1 row scaled by KTAN; fc2 folded
      fcb = KTAN * fc1_b[u];
      const float w2 = fc2_w[u];
      fc2w2 = 2.f * w2; fc2wn = -w2;
#pragma unroll
      for (int j = 0; j < NH; ++j) fcw[j] = KTAN * fc1_w[u*NH + j];
    }
  } else {
    if (u < NH) {
      const int ri = 0*NH+u, rf = 1*NH+u, rg = 2*NH+u, ro = 3*NH+u;
      bb_if.x = KSIG * (b_ih1[ri] + b_hh1[ri]); bb_if.y = KSIG * (b_ih1[rf] + b_hh1[rf]);
      bb_go.x = KTAN * (b_ih1[rg] + b_hh1[rg]); bb_go.y = KSIG * (b_ih1[ro] + b_hh1[ro]);
#pragma unroll
      for (int j = 0; j < NH; ++j) {
        wIF[j].x = KSIG * w_ih1[ri*NH+j]; wIF[j].y = KSIG * w_ih1[rf*NH+j];
        wGO[j].x = KTAN * w_ih1[rg*NH+j]; wGO[j].y = KSIG * w_ih1[ro*NH+j];
        vIF[j].x = KSIG * w_hh1[ri*NH+j]; vIF[j].y = KSIG * w_hh1[rf*NH+j];
        vGO[j].x = KTAN * w_hh1[rg*NH+j]; vGO[j].y = KSIG * w_hh1[ro*NH+j];
      }
    }
  }

  const float* xp   = x + (size_t)seq * T_LEN;
  float*       outp = out + (size_t)seq * OUT_T;

  float c = 0.f;                                  // KTAN-scaled cell state
  float r0=0.f,r1=0.f,r2=0.f,r3=0.f,r4=0.f,r5=0.f,r6=0.f,r7=0.f,r8=0.f,r9=0.f;

  // ---- A: produce h0 for steps m*CH .. m*CH+CH-1 into h0buf[m&1] ----
  auto a_chunk = [&](int m) {
    float* hb = &h0buf[m & 1][0][0];
    const float* hr = &h0buf[m & 1][0][grp * 16];
    const float4* xq = (const float4*)(xp + m * CH);
    float4 xw[CH / 4];
#pragma unroll
    for (int i = 0; i < CH / 4; ++i) xw[i] = xq[i];
#pragma unroll
    for (int s = 0; s < CH; ++s) {
      const float xv = ((const float*)xw)[s];
      v2f aA = fma2(wx_if, splat2(xv), bb_if);
      v2f gA = fma2(wx_go, splat2(xv), bb_go);
      v2f aB = mulsp(wIF[1], r1);
      v2f gB = mulsp(wGO[1], r1);
#define L0T(j, hv, AC, GC) { const v2f sp = splat2(hv); \
      AC = fma2(wIF[j], sp, AC); GC = fma2(wGO[j], sp, GC); }
      L0T(0,r0,aA,gA) L0T(2,r2,aA,gA) L0T(3,r3,aB,gB) L0T(4,r4,aA,gA)
      L0T(5,r5,aB,gB) L0T(6,r6,aA,gA) L0T(7,r7,aB,gB) L0T(8,r8,aA,gA)
      L0T(9,r9,aB,gB)
#undef L0T
      const v2f gif = aA + aB;            // pre-scaled gate values
      const v2f ggo = gA + gB;
      const float si = rcp1p(__builtin_amdgcn_exp2f(gif.x));
      const float sf = rcp1p(__builtin_amdgcn_exp2f(gif.y));
      const float rg = rcp1p(__builtin_amdgcn_exp2f(ggo.x));
      const float so = rcp1p(__builtin_amdgcn_exp2f(ggo.y));
      const float tgp = __builtin_fmaf(rg, 2.f*KTAN, -KTAN);  // KTAN*tanh(g)
      c = __builtin_fmaf(sf, c, si * tgp);                    // c' = KTAN*c
      const float rc = rcp1p(__builtin_amdgcn_exp2f(c));
      const float tc = __builtin_fmaf(rc, 2.f, -1.f);         // tanh(c)
      const float h0n = so * tc;                              // true h0
      hb[s*64 + lane] = h0n;
      const float4 va = *(const float4*)(hr + s*64);
      const float4 vb = *(const float4*)(hr + s*64 + 4);
      const float2 vc = *(const float2*)(hr + s*64 + 8);
      r0=va.x; r1=va.y; r2=va.z; r3=va.w;
      r4=vb.x; r5=vb.y; r6=vb.z; r7=vb.w;
      r8=vc.x; r9=vc.y;
    }
  };

  // ---- B: consume h0 chunk m, produce h1 chunk m into h1buf[m&1] ----
  auto b_chunk = [&](int m) {
    const float* hbi = &h0buf[m & 1][0][grp * 16];
    float* ob = &h1buf[m & 1][0][0];
    const float* orr = &h1buf[m & 1][0][grp * 16];
#pragma unroll
    for (int s = 0; s < CH; ++s) {
      const float4 pa = *(const float4*)(hbi + s*64);
      const float4 pb = *(const float4*)(hbi + s*64 + 4);
      const float2 pc = *(const float2*)(hbi + s*64 + 8);
      v2f cA = fma2(wIF[0], splat2(pa.x), bb_if);
      v2f hA = fma2(wGO[0], splat2(pa.x), bb_go);
      v2f cB = mulsp(wIF[1], pa.y);
      v2f hB = mulsp(wGO[1], pa.y);
#define L1I(j, hv, AC, GC) { const v2f sp = splat2(hv); \
      AC = fma2(wIF[j], sp, AC); GC = fma2(wGO[j], sp, GC); }
      L1I(2,pa.z,cA,hA) L1I(3,pa.w,cB,hB) L1I(4,pb.x,cA,hA) L1I(5,pb.y,cB,hB)
      L1I(6,pb.z,cA,hA) L1I(7,pb.w,cB,hB) L1I(8,pc.x,cA,hA) L1I(9,pc.y,cB,hB)
#undef L1I
      v2f cC = mulsp(vIF[0], r0);
      v2f hC = mulsp(vGO[0], r0);
      v2f cD = mulsp(vIF[1], r1);
      v2f hD = mulsp(vGO[1], r1);
#define L1R(j, hv, AC, GC) { const v2f sp = splat2(hv); \
      AC = fma2(vIF[j], sp, AC); GC = fma2(vGO[j], sp, GC); }
      L1R(2,r2,cC,hC) L1R(3,r3,cD,hD) L1R(4,r4,cC,hC) L1R(5,r5,cD,hD)
      L1R(6,r6,cC,hC) L1R(7,r7,cD,hD) L1R(8,r8,cC,hC) L1R(9,r9,cD,hD)
#undef L1R
      const v2f gif = (cA + cB) + (cC + cD);
      const v2f ggo = (hA + hB) + (hC + hD);
      const float si = rcp1p(__builtin_amdgcn_exp2f(gif.x));
      const float sf = rcp1p(__builtin_amdgcn_exp2f(gif.y));
      const float rg = rcp1p(__builtin_amdgcn_exp2f(ggo.x));
      const float so = rcp1p(__builtin_amdgcn_exp2f(ggo.y));
      const float tgp = __builtin_fmaf(rg, 2.f*KTAN, -KTAN);
      c = __builtin_fmaf(sf, c, si * tgp);
      const float rc = rcp1p(__builtin_amdgcn_exp2f(c));
      const float tc = __builtin_fmaf(rc, 2.f, -1.f);
      const float h1n = so * tc;                              // true h1
      ob[s*64 + lane] = h1n;
      const float4 va = *(const float4*)(orr + s*64);
      const float4 vb = *(const float4*)(orr + s*64 + 4);
      const float2 vc = *(const float2*)(orr + s*64 + 8);
      r0=va.x; r1=va.y; r2=va.z; r3=va.w;
      r4=vb.x; r5=vb.y; r6=vb.z; r7=vb.w;
      r8=vc.x; r9=vc.y;
    }
  };

  // ---- A also runs the fc head on h1 chunk m (two rounds behind) ----
  auto fc_chunk = [&](int m) {
    const float* hb = &h1buf[m & 1][0][grp * 16];
    float* oq = outp + (m * CH - TFIRST);
#pragma unroll
    for (int s = 0; s < CH; ++s) {
      if (m * CH + s < TFIRST + OUT_T) {          // t <= 2046
        const float4 pa = *(const float4*)(hb + s*64);
        const float4 pb = *(const float4*)(hb + s*64 + 4);
        const float2 pc = *(const float2*)(hb + s*64 + 8);
        float acc = __builtin_fmaf(pa.x, fcw[0], fcb);        // KTAN-scaled
        acc = __builtin_fmaf(pa.y, fcw[1], acc);
        acc = __builtin_fmaf(pa.z, fcw[2], acc);
        acc = __builtin_fmaf(pa.w, fcw[3], acc);
        acc = __builtin_fmaf(pb.x, fcw[4], acc);
        acc = __builtin_fmaf(pb.y, fcw[5], acc);
        acc = __builtin_fmaf(pb.z, fcw[6], acc);
        acc = __builtin_fmaf(pb.w, fcw[7], acc);
        acc = __builtin_fmaf(pc.x, fcw[8], acc);
        acc = __builtin_fmaf(pc.y, fcw[9], acc);
        const float rc = rcp1p(__builtin_amdgcn_exp2f(acc));
        float y = __builtin_fmaf(rc, fc2w2, fc2wn);           // fc2_w*tanh(acc)
        y += ROR_F(y, 8);
        y += ROR_F(y, 4);
        y += ROR_F(y, 2);
        y += ROR_F(y, 1);                         // whole 16-group holds sum
        if (u == 0) oq[s] = y + fc2bl;
      }
    }
  };

  // ---- pipeline: round r = {A: L0 chunk r, fc chunk r-2 ; B: L1 chunk r-1} ----
#pragma unroll 1
  for (int r = 0; r < NCH + 2; ++r) {
    if (wid == 0) {
      if (r < NCH) a_chunk(r);
      const int m = r - 2;
      if (m >= MFIRST && m < NCH) fc_chunk(m);
    } else {
      if (r >= 1 && r <= NCH) b_chunk(r - 1);
    }
    __syncthreads();
  }
}

extern "C" void kernel_launch(void* const* d_in, const int* in_sizes, int n_in,
                              void* d_out, int out_size, void* d_ws, size_t ws_size,
                              hipStream_t stream) {
  const float* x     = (const float*)d_in[0];
  const float* w_ih0 = (const float*)d_in[1];
  const float* w_hh0 = (const float*)d_in[2];
  const float* b_ih0 = (const float*)d_in[3];
  const float* b_hh0 = (const float*)d_in[4];
  const float* w_ih1 = (const float*)d_in[5];
  const float* w_hh1 = (const float*)d_in[6];
  const float* b_ih1 = (const float*)d_in[7];
  const float* b_hh1 = (const float*)d_in[8];
  const float* fc1_w = (const float*)d_in[9];
  const float* fc1_b = (const float*)d_in[10];
  const float* fc2_w = (const float*)d_in[11];
  const float* fc2_b = (const float*)d_in[12];
  float* out = (float*)d_out;

  lstm_fused<<<dim3(NSEQ / 4), dim3(128), 0, stream>>>(
      x, w_ih0, w_hh0, b_ih0, b_hh0, w_ih1, w_hh1, b_ih1, b_hh1,
      fc1_w, fc1_b, fc2_w, fc2_b, out);
}